// Round 1
// 321.523 us; speedup vs baseline: 1.3399x; 1.3399x over previous
//
#include <hip/hip_runtime.h>

#define D_  256
#define K_  1024
#define HW_ 1024      // 32*32
#define N_  32768     // 32*HW_

// workspace layout (bytes)
#define WS_IDX     0          // int32[32768]
#define WS_COUNTS  131072     // f32[1024]
#define WS_EMBSUM  135168     // f32[262144]
#define WS_LOSS    1183744    // f32
#define WS_NSUM    1183748    // f32
#define WS_NEWCS   1183752    // f32[1024]
#define WS_ENORM   1187848    // f32[1024]
#define WS_ZNORM   1191944    // f32[32768]
#define WS_ENMAX   1323016    // u32 (max ||e||^2 bits)
#define WS_E16     1323024    // bf16[1024*256] = 512 KiB (written fully by norms)
#define WS_ZERO    1323020    // memset range (E16 needs no zeroing)
#define WS_TOTAL   1847312

// output offsets (f32 elements): (z_q_st, loss, indices, new_emb, new_cs, new_es)
#define O_ZQ   0
#define O_LOSS 8388608
#define O_IDX  8388609
#define O_EMB  8421377
#define O_NCS  8683521
#define O_NES  8684545

typedef unsigned short u16;
typedef short bf16x8 __attribute__((ext_vector_type(8)));  // 8 bf16 = 4 VGPRs
typedef float f32x4 __attribute__((ext_vector_type(4)));

// round-to-nearest-even f32 -> bf16 (data has no NaN)
__device__ __forceinline__ unsigned bf16rne(float x) {
  unsigned u = __float_as_uint(x);
  return (u + 0x7FFFu + ((u >> 16) & 1u)) >> 16;
}

// numpy pairwise_sum of 256 squares: two 128-halves, 8 accumulators,
// combine ((r0+r1)+(r2+r3))+((r4+r5)+(r6+r7)). __f*_rn blocks FMA contraction.
__device__ __forceinline__ float pw256_sq(const float* __restrict__ p, int stride) {
  float tot0 = 0.f, tot1 = 0.f;
#pragma unroll
  for (int h = 0; h < 2; ++h) {
    const float* q = p + h * 128 * stride;
    float r[8];
#pragma unroll
    for (int j = 0; j < 8; ++j) { float x = q[j * stride]; r[j] = __fmul_rn(x, x); }
    for (int i = 8; i < 128; i += 8)
#pragma unroll
      for (int j = 0; j < 8; ++j) {
        float x = q[(i + j) * stride];
        r[j] = __fadd_rn(r[j], __fmul_rn(x, x));
      }
    float s = __fadd_rn(__fadd_rn(__fadd_rn(r[0], r[1]), __fadd_rn(r[2], r[3])),
                        __fadd_rn(__fadd_rn(r[4], r[5]), __fadd_rn(r[6], r[7])));
    if (h == 0) tot0 = s; else tot1 = s;
  }
  return __fadd_rn(tot0, tot1);
}

// ---------------- ||z_n||^2, ||e_k||^2 (np order), en_max, E->bf16 ----------------
__global__ void vq_norms_v8(const float* __restrict__ z, const float* __restrict__ E,
                            float* __restrict__ znorm, float* __restrict__ enorm,
                            u16* __restrict__ E16, unsigned* __restrict__ enmax) {
  int t = blockIdx.x * 128 + threadIdx.x;        // 264 x 128 = 33792
  if (t < N_) {
    const float* p = z + (t >> 10) * (D_ * HW_) + (t & 1023);  // stride HW_ over d
    znorm[t] = pw256_sq(p, HW_);
  } else if (t < N_ + K_) {
    int k = t - N_;
    float v = pw256_sq(E + k * D_, 1);
    enorm[k] = v;
    atomicMax(enmax, __float_as_uint(v));        // v > 0 -> bit-monotone
  }
  // E -> bf16, element-parallel grid-stride, coalesced pair loads/stores
  unsigned* E16w = (unsigned*)E16;
  int gsz = gridDim.x * 128;
  for (int wd = t; wd < (K_ * D_ / 2); wd += gsz) {
    float2 x = *(const float2*)(E + 2 * wd);
    E16w[wd] = bf16rne(x.x) | (bf16rne(x.y) << 16);
  }
}

// Exact reference-numerics distance for one (token, code): sequential fp32 FMA
// chain over d=0..255 (byte-identical to the passing v9 path), then
// fl(fl(zn - 2a) + en). Lexicographic (score,code) min => np argmin tie-break.
__device__ __forceinline__ void exact_update(
    const float* __restrict__ zb, const float* __restrict__ E,
    int t, int c, const float* __restrict__ zn_s, const float* __restrict__ en_s,
    unsigned long long* __restrict__ best_s) {
  const float* zp = zb + t;             // stride HW_ over d (original f32 z)
  const float* ep = E + c * D_;
  float a = 0.f;
  for (int d0 = 0; d0 < 256; d0 += 8) {
    float zr[8], er[8];
#pragma unroll
    for (int j = 0; j < 8; ++j) { zr[j] = zp[(d0 + j) * HW_]; er[j] = ep[d0 + j]; }
#pragma unroll
    for (int j = 0; j < 8; ++j) a = __fmaf_rn(zr[j], er[j], a);
  }
  float s = __fadd_rn(__fsub_rn(zn_s[t], __fmul_rn(2.0f, a)), en_s[c]);
  // s ~ 200..330 > 0 -> float bits monotone; low 32 bits = code (lowest idx wins ties)
  unsigned long long key = ((unsigned long long)__float_as_uint(s) << 32) | (unsigned)c;
  atomicMin(&best_s[t], key);
}

#define TCAP 768   // per-wave trigger-list capacity (expected ~100-200 used)

// ---------------- MFMA distance + argmin with exact verification ----------------
// 512 blocks x 256 thr. Block = 64 tokens (one b, 64 consecutive hw) x all 1024
// codes. Wave w owns codes [w*256,(w+1)*256) in 4 chunks of 64. bf16 MFMA gives
// approx scores ph = en - 2*(z.e); per-token shared running min (LDS atomicMin on
// ph+4 bits); any ph within margin M of runmin is exactly recomputed.
// M = 2^-4*sqrt(zn*en_max)+2e-4 = 2x the worst-case two-sided bf16 error bound
// (per-side <= 2^-6*||z||*||e|| + 6.6e-5), so the reference argmin always triggers.
__global__ __launch_bounds__(256, 2) void vq_dist_mfma(
    const float* __restrict__ z, const float* __restrict__ E,
    const u16* __restrict__ E16,
    const float* __restrict__ znorm, const float* __restrict__ enorm,
    const unsigned* __restrict__ enmax,
    int* __restrict__ idx_out, float* __restrict__ counts) {
  // z tile as bf16 in [kb=d>>3][tok][8d] subtiles: frag ds_read_b128 is
  // conflict-free (64 lanes -> 64 consecutive 16B slots), no swizzle needed.
  __shared__ __align__(16) u16 zt[32 * 64 * 8];          // 32 KiB
  __shared__ float en_s[K_];                              // 4 KiB
  __shared__ float zn_s[64];
  __shared__ float mg_s[64];
  __shared__ unsigned rmin_s[64];                         // bits of (min ph)+4.0
  __shared__ unsigned long long best_s[64];
  __shared__ unsigned tcount[4];
  __shared__ unsigned tlist[4][TCAP];                     // 12 KiB

  const int tid = threadIdx.x;
  const int bimg = blockIdx.x >> 4;          // 16 blocks per image
  const int hw0 = (blockIdx.x & 15) << 6;
  const float* zb = z + bimg * (D_ * HW_) + hw0;

  if (tid < 64) {
    float zn = znorm[bimg * HW_ + hw0 + tid];
    zn_s[tid] = zn;
    float em = __uint_as_float(*enmax);
    mg_s[tid] = 0.0625f * sqrtf(zn * em) + 2e-4f;   // margin M (proven safe)
    rmin_s[tid] = 0xFFFFFFFFu;                       // +inf (never read as float
    best_s[tid] = ~0ull;                             //  before first update)
  }
  if (tid < 4) tcount[tid] = 0;
  for (int i = tid; i < K_; i += 256) en_s[i] = enorm[i];

  // stage z tile -> bf16 LDS. thread: tok = tid&63, kb = (tid>>6)*8 + r.
  // global: 64 lanes read 64 consecutive floats per instr (256B coalesced).
  {
    const int tok = tid & 63;
    const int kbase = (tid >> 6) * 8;
    for (int r = 0; r < 8; ++r) {
      int kb = kbase + r;
      unsigned pk[4];
#pragma unroll
      for (int j = 0; j < 4; ++j) {
        float x0 = zb[(kb * 8 + 2 * j) * HW_ + tok];
        float x1 = zb[(kb * 8 + 2 * j + 1) * HW_ + tok];
        pk[j] = bf16rne(x0) | (bf16rne(x1) << 16);
      }
      uint4 wv; wv.x = pk[0]; wv.y = pk[1]; wv.z = pk[2]; wv.w = pk[3];
      *(uint4*)(zt + kb * 512 + tok * 8) = wv;       // 16B, conflict-free
    }
  }
  __syncthreads();

  const int lane = tid & 63;
  const int w = tid >> 6;
  const int l15 = lane & 15, g = lane >> 4;

  for (int ch = 0; ch < 4; ++ch) {
    const int cb = w * 256 + ch * 64;
    f32x4 acc[4][4];                                  // [m-tile][n-tile]
    {
      f32x4 z4 = {0.f, 0.f, 0.f, 0.f};
#pragma unroll
      for (int m = 0; m < 4; ++m)
#pragma unroll
        for (int n = 0; n < 4; ++n) acc[m][n] = z4;
    }
    for (int kk = 0; kk < 8; ++kk) {
      bf16x8 ef[4], zf[4];
      // B-frag: row = code (lane&15 within n-tile), k = kk*32 + g*8 + j
#pragma unroll
      for (int n = 0; n < 4; ++n)
        ef[n] = *(const bf16x8*)(E16 + (unsigned)(cb + n * 16 + l15) * D_ + kk * 32 + g * 8);
      // A-frag: row = token (lane&15 within m-tile), same k slice
#pragma unroll
      for (int m = 0; m < 4; ++m)
        zf[m] = *(const bf16x8*)(zt + (kk * 4 + g) * 512 + (m * 16 + l15) * 8);
#pragma unroll
      for (int m = 0; m < 4; ++m)
#pragma unroll
        for (int n = 0; n < 4; ++n)
          acc[m][n] = __builtin_amdgcn_mfma_f32_16x16x32_bf16(zf[m], ef[n], acc[m][n], 0, 0, 0);
    }
    // ph = en - 2*acc in-place. D layout: col=lane&15 (code), row=g*4+r (token).
    float enc[4];
#pragma unroll
    for (int n = 0; n < 4; ++n) enc[n] = en_s[cb + n * 16 + l15];
#pragma unroll
    for (int m = 0; m < 4; ++m)
#pragma unroll
      for (int n = 0; n < 4; ++n)
#pragma unroll
        for (int r = 0; r < 4; ++r)
          acc[m][n][r] = __builtin_fmaf(-2.0f, acc[m][n][r], enc[n]);
    // chunk-min per token -> shared running min (biased +4: ph in (-0.2,0.2))
#pragma unroll
    for (int m = 0; m < 4; ++m) {
#pragma unroll
      for (int r = 0; r < 4; ++r) {
        float v = fminf(fminf(acc[m][0][r], acc[m][1][r]),
                        fminf(acc[m][2][r], acc[m][3][r]));
        v = fminf(v, __shfl_xor(v, 1, 16));
        v = fminf(v, __shfl_xor(v, 2, 16));
        v = fminf(v, __shfl_xor(v, 4, 16));
        v = fminf(v, __shfl_xor(v, 8, 16));
        if (l15 == 0) atomicMin(&rmin_s[m * 16 + g * 4 + r], __float_as_uint(v + 4.0f));
      }
    }
    // triggers: ph <= runmin + M  (stale/larger runmin is safe: more triggers)
#pragma unroll
    for (int m = 0; m < 4; ++m) {
#pragma unroll
      for (int r = 0; r < 4; ++r) {
        int t = m * 16 + g * 4 + r;
        float thr = (__uint_as_float(rmin_s[t]) - 4.0f) + mg_s[t];
#pragma unroll
        for (int n = 0; n < 4; ++n) {
          if (acc[m][n][r] <= thr) {
            int c = cb + n * 16 + l15;
            unsigned pos = atomicAdd(&tcount[w], 1u);
            if (pos < TCAP) tlist[w][pos] = ((unsigned)t << 16) | (unsigned)c;
            else exact_update(zb, E, t, c, zn_s, en_s, best_s);  // never in practice
          }
        }
      }
    }
  }

  // drain own wave's trigger list: exact recompute, lexicographic argmin
  {
    unsigned cnt = tcount[w];
    if (cnt > TCAP) cnt = TCAP;
    for (unsigned base = 0; base < cnt; base += 64) {
      unsigned i = base + (unsigned)lane;
      if (i < cnt) {
        unsigned e = tlist[w][i];
        exact_update(zb, E, (int)(e >> 16), (int)(e & 1023u), zn_s, en_s, best_s);
      }
    }
  }
  __syncthreads();
  if (tid < 64) {
    int bi = (int)(best_s[tid] & 1023ull);
    idx_out[bimg * HW_ + hw0 + tid] = bi;
    atomicAdd(&counts[bi], 1.0f);
  }
}

// ---------------- z_q_st + loss + embed_sum + index output (all f32) ----------------
__global__ __launch_bounds__(256, 1) void vq_scatter_v7(
    const float* __restrict__ z, const float* __restrict__ E,
    const int* __restrict__ idx_in, float* __restrict__ embsum,
    float* __restrict__ loss_sum, float* __restrict__ out_zq,
    float* __restrict__ out_idx) {
  __shared__ float zt[256 * 33];     // staged z, overwritten in-place with z_q_st
  __shared__ int idx_s[32];
  __shared__ float wred[4];
  const int tid = threadIdx.x;
  const int tile = blockIdx.x;       // 0..1023
  const int b = tile >> 5;
  const int hw0 = (tile & 31) * 32;
  const float* zb = z + b * (D_ * HW_) + hw0;
  if (tid < 32) {
    int k = idx_in[b * HW_ + hw0 + tid] & 1023;   // clamp: no wild gather ever
    idx_s[tid] = k;
    out_idx[b * HW_ + hw0 + tid] = (float)k;
  }
#pragma unroll
  for (int r = 0; r < 8; ++r) {
    int ii = r * 256 + tid;
    int d = ii >> 3, t4 = (ii & 7) * 4;
    float4 v = *(const float4*)(zb + d * HW_ + t4);
    float* p = zt + d * 33 + t4;
    p[0] = v.x; p[1] = v.y; p[2] = v.z; p[3] = v.w;
  }
  __syncthreads();

  const int w = tid >> 6, lane = tid & 63;
  float lsum = 0.f;
  for (int tt = 0; tt < 8; ++tt) {
    int t = w * 8 + tt;
    int k = idx_s[t];                      // wave-uniform
    const float* Er = E + k * D_;
    float* es = embsum + k * D_;
#pragma unroll
    for (int i = 0; i < 4; ++i) {
      int d = i * 64 + lane;
      float e = Er[d];
      float zv = zt[d * 33 + t];           // unique (t,d) owner -> safe in-place
      float df = __fsub_rn(zv, e);
      lsum += df * df;
      zt[d * 33 + t] = __fadd_rn(zv, __fsub_rn(e, zv));  // ref: z + (z_q - z)
      atomicAdd(es + d, zv);
    }
  }
#pragma unroll
  for (int o = 32; o > 0; o >>= 1) lsum += __shfl_down(lsum, o, 64);
  if (lane == 0) wred[w] = lsum;
  __syncthreads();
  if (tid == 0) atomicAdd(loss_sum, wred[0] + wred[1] + wred[2] + wred[3]);

  float* ob = out_zq + b * (D_ * HW_) + hw0;
#pragma unroll 4
  for (int r = 0; r < 32; ++r) {
    int d = r * 8 + (tid >> 5);
    int t = tid & 31;
    ob[d * HW_ + t] = zt[d * 33 + t];      // coalesced 128B-chunk f32 stores
  }
}

// ---------------- EMA cluster-size + n + loss finalize ----------------
__global__ void vq_newcs_v7(const float* __restrict__ cs_in, const float* __restrict__ counts,
                            float* __restrict__ newcs, float* __restrict__ nsum,
                            const float* __restrict__ loss_sum,
                            float* __restrict__ out_loss, float* __restrict__ out_ncs) {
  int k = blockIdx.x * 256 + threadIdx.x;
  float v = __fadd_rn(__fmul_rn(0.99f, cs_in[k]), __fmul_rn(0.01f, counts[k]));
  newcs[k] = v;
  out_ncs[k] = v;
  float s = v;
#pragma unroll
  for (int o = 32; o > 0; o >>= 1) s += __shfl_down(s, o, 64);
  __shared__ float w[4];
  if ((threadIdx.x & 63) == 0) w[threadIdx.x >> 6] = s;
  __syncthreads();
  if (threadIdx.x == 0) atomicAdd(nsum, w[0] + w[1] + w[2] + w[3]);
  if (k == 0) out_loss[0] = loss_sum[0] * (1.0f / 8388608.0f);
}

// ---------------- new_es + new_embedding ----------------
__global__ void vq_newemb_v7(const float* __restrict__ es_in, const float* __restrict__ embsum,
                             const float* __restrict__ newcs, const float* __restrict__ nsum,
                             float* __restrict__ out_emb, float* __restrict__ out_nes) {
  int k = blockIdx.x, d = threadIdx.x;
  float n = *nsum;
  float cs = (newcs[k] + 1e-5f) / (n + 1024.0f * 1e-5f) * n;   // ref formula order
  float es = __fadd_rn(__fmul_rn(0.99f, es_in[k * D_ + d]),
                       __fmul_rn(0.01f, embsum[k * D_ + d]));
  out_nes[k * D_ + d] = es;
  out_emb[k * D_ + d] = es / cs;
}

extern "C" void kernel_launch(void* const* d_in, const int* in_sizes, int n_in,
                              void* d_out, int out_size, void* d_ws, size_t ws_size,
                              hipStream_t stream) {
  (void)in_sizes; (void)n_in; (void)out_size; (void)ws_size;
  const float* z       = (const float*)d_in[0];
  const float* E       = (const float*)d_in[1];
  const float* ema_cs  = (const float*)d_in[2];
  const float* ema_es  = (const float*)d_in[3];
  float* out = (float*)d_out;
  char* ws = (char*)d_ws;
  int*   ws_idx = (int*)(ws + WS_IDX);
  float* counts = (float*)(ws + WS_COUNTS);
  float* embsum = (float*)(ws + WS_EMBSUM);
  float* loss_s = (float*)(ws + WS_LOSS);
  float* nsum   = (float*)(ws + WS_NSUM);
  float* newcs  = (float*)(ws + WS_NEWCS);
  float* enorm  = (float*)(ws + WS_ENORM);
  float* znorm  = (float*)(ws + WS_ZNORM);
  unsigned* enmax = (unsigned*)(ws + WS_ENMAX);
  u16*   e16    = (u16*)(ws + WS_E16);

  hipMemsetAsync(d_ws, 0, WS_ZERO, stream);
  vq_norms_v8<<<dim3(264), dim3(128), 0, stream>>>(z, E, znorm, enorm, e16, enmax);
  vq_dist_mfma<<<dim3(512), dim3(256), 0, stream>>>(z, E, e16, znorm, enorm, enmax,
                                                    ws_idx, counts);
  vq_scatter_v7<<<dim3(1024), dim3(256), 0, stream>>>(z, E, ws_idx, embsum, loss_s,
                                                      out + O_ZQ, out + O_IDX);
  vq_newcs_v7<<<dim3(4), dim3(256), 0, stream>>>(ema_cs, counts, newcs, nsum, loss_s,
                                                 out + O_LOSS, out + O_NCS);
  vq_newemb_v7<<<dim3(K_), dim3(256), 0, stream>>>(ema_es, embsum, newcs, nsum,
                                                   out + O_EMB, out + O_NES);
}